// Round 1
// baseline (56.246 us; speedup 1.0000x reference)
//
#include <hip/hip_runtime.h>
#include <math.h>

#define COLS_PER_BLOCK 256
#define CHUNK 64

// ---------------------------------------------------------------------------
// Kernel 1: compute nw = min(ceil(log(0.01, beta_max)) + 1, 100) on device.
// beta = sigmoid(beta_raw) * 0.9999 ; sigmoid is monotone so reduce raw max.
// ---------------------------------------------------------------------------
__global__ void garch_nw_kernel(const float* __restrict__ beta_raw, int N,
                                int* __restrict__ nw_out) {
    __shared__ float red[256];
    float m = -1e30f;
    for (int i = threadIdx.x; i < N; i += blockDim.x)
        m = fmaxf(m, beta_raw[i]);
    red[threadIdx.x] = m;
    __syncthreads();
    for (int s = 128; s > 0; s >>= 1) {
        if ((int)threadIdx.x < s)
            red[threadIdx.x] = fmaxf(red[threadIdx.x], red[threadIdx.x + s]);
        __syncthreads();
    }
    if (threadIdx.x == 0) {
        float braw = red[0];
        float beta = (1.0f / (1.0f + expf(-braw))) * 0.9999f;
        double bm = (double)beta;
        // Python: math.log(0.01, beta_max) = log(0.01)/log(beta_max), double
        double r = log(0.01) / log(bm);
        int nw = (int)ceil(r) + 1;
        if (nw > 100) nw = 100;
        if (nw < 1) nw = 1;
        nw_out[0] = nw;
    }
}

// ---------------------------------------------------------------------------
// Kernel 2: per (column n, t-chunk) thread.
//   a[t] = sum_{j=0..nw-1} beta^j * x2[t-1-j]   (x2 = x*x, zero for t<0)
//   recursion: a[t+1] = x2[t] + beta*a[t] - beta^nw * x2[t-nw]
//   sigma[t] = sqrt(w0 + alpha * a[t]),  w0 = omega^2/(1-beta)
// ---------------------------------------------------------------------------
__global__ __launch_bounds__(COLS_PER_BLOCK) void garch_sigma_kernel(
    const float* __restrict__ x,
    const float* __restrict__ alpha_raw,
    const float* __restrict__ beta_raw,
    const float* __restrict__ omega_raw,
    float* __restrict__ out,
    const int* __restrict__ nw_ptr,
    int T, int N) {

    const int n = blockIdx.x * COLS_PER_BLOCK + threadIdx.x;
    if (n >= N) return;
    const int t0 = blockIdx.y * CHUNK;
    const int nw = *nw_ptr;

    const float alpha = 1.0f / (1.0f + expf(-alpha_raw[n]));
    const float beta  = (1.0f / (1.0f + expf(-beta_raw[n]))) * 0.9999f;
    const float om    = 1.0f / (1.0f + expf(-omega_raw[n]));
    const float w0    = om * om / (1.0f - beta);

    const float* __restrict__ xc = x + n;

    // ---- initial 100-tap FIR for a[t0]; running weight ends at beta^nw ----
    float acc = 0.0f;
    float w   = 1.0f;
    #pragma unroll 4
    for (int j = 0; j < nw; ++j) {
        const int r = t0 - 1 - j;
        float xv = 0.0f;
        if (r >= 0) xv = xc[(size_t)r * N];
        acc = fmaf(w, xv * xv, acc);
        w *= beta;
    }
    const float bnw = w;  // beta^nw, consistent with FIR weights

    // ---- recursion over the chunk ----
    const int tend = (t0 + CHUNK < T) ? (t0 + CHUNK) : T;
    for (int t = t0; t < tend; ++t) {
        const float var = fmaf(alpha, acc, w0);
        out[(size_t)t * N + n] = sqrtf(var);

        const float xt = xc[(size_t)t * N];
        const int   to = t - nw;
        const float xo = (to >= 0) ? xc[(size_t)to * N] : 0.0f;
        acc = fmaf(beta, acc, xt * xt) - bnw * (xo * xo);
    }
}

// ---------------------------------------------------------------------------
extern "C" void kernel_launch(void* const* d_in, const int* in_sizes, int n_in,
                              void* d_out, int out_size, void* d_ws, size_t ws_size,
                              hipStream_t stream) {
    const float* x   = (const float*)d_in[0];
    const float* ar  = (const float*)d_in[1];
    const float* br  = (const float*)d_in[2];
    const float* orw = (const float*)d_in[3];
    float* out = (float*)d_out;

    const int N = in_sizes[1];          // alpha_raw is [1, N]
    const int T = in_sizes[0] / N;      // x is [T, N]

    int* nwp = (int*)d_ws;

    hipLaunchKernelGGL(garch_nw_kernel, dim3(1), dim3(256), 0, stream, br, N, nwp);

    dim3 grid((N + COLS_PER_BLOCK - 1) / COLS_PER_BLOCK,
              (T + CHUNK - 1) / CHUNK);
    hipLaunchKernelGGL(garch_sigma_kernel, grid, dim3(COLS_PER_BLOCK), 0, stream,
                       x, ar, br, orw, out, nwp, T, N);
}